// Round 5
// baseline (117.457 us; speedup 1.0000x reference)
//
#include <hip/hip_runtime.h>

// x, enhance_x : (16, 3, 512, 512) fp32.
// q[b,i,j] = mean_{c,4x4}(x) - mean_{c,4x4}(e)  (128x128 per batch)
// out[b,i,j] = sum over 4 dirs of (q_c - q_nb)^2, zero-padded neighbors.
//
// Fused single kernel: each block computes a 16x32 q-tile plus 1-pixel halo
// (18x34) into LDS via direct pooling of the inputs (halo recompute overlap
// mostly L2-absorbed), then the 4-direction loss from LDS.
// Grid: 16 batches x (8 row-tiles x 4 col-tiles) = 512 blocks of 512 threads.

__global__ __launch_bounds__(512) void spatial_loss_fused(
    const float* __restrict__ x, const float* __restrict__ e,
    float* __restrict__ out)
{
    __shared__ float sq[18][35];     // +1 pad: odd stride -> conflict-free

    int blk = blockIdx.x;            // 0..511: b*32 + ti*4 + tj
    int b  = blk >> 5;
    int ti = (blk >> 2) & 7;         // row tile 0..7  (16 q-rows each)
    int tj = blk & 3;                // col tile 0..3  (32 q-cols each)
    int tid = threadIdx.x;

    // Batch base in float4 units: b * 3ch * 512rows * 128 float4/row
    const float4* xb = reinterpret_cast<const float4*>(x) + (size_t)b * 3 * 512 * 128;
    const float4* eb = reinterpret_cast<const float4*>(e) + (size_t)b * 3 * 512 * 128;

    // Phase 1: fill 18x34 halo'd q-tile (612 entries, 512 threads -> <=2 each)
    for (int k = tid; k < 18 * 34; k += 512) {
        int hy = k / 34, hx = k - hy * 34;
        int qi = ti * 16 - 1 + hy;         // -1 .. 128
        int qj = tj * 32 - 1 + hx;
        float v = 0.0f;                    // zero-pad outside [0,128)
        if ((unsigned)qi < 128u && (unsigned)qj < 128u) {
            int row0 = qi << 2;
            float sx = 0.0f, se = 0.0f;
#pragma unroll
            for (int c = 0; c < 3; ++c) {
#pragma unroll
                for (int di = 0; di < 4; ++di) {
                    int off = (c * 512 + row0 + di) * 128 + qj;
                    float4 vx = xb[off];
                    float4 ve = eb[off];
                    sx += (vx.x + vx.y) + (vx.z + vx.w);
                    se += (ve.x + ve.y) + (ve.z + ve.w);
                }
            }
            v = (sx - se) * (1.0f / 48.0f);
        }
        sq[hy][hx] = v;
    }
    __syncthreads();

    // Phase 2: 16x32 outputs, one per thread
    int ly = tid >> 5, lx = tid & 31;
    float qc = sq[ly + 1][lx + 1];
    float dl = qc - sq[ly + 1][lx];
    float dr = qc - sq[ly + 1][lx + 2];
    float du = qc - sq[ly][lx + 1];
    float dd = qc - sq[ly + 2][lx + 1];
    int qi = ti * 16 + ly, qj = tj * 32 + lx;
    out[((size_t)b << 14) + (qi << 7) + qj] = dl * dl + dr * dr + du * du + dd * dd;
}

extern "C" void kernel_launch(void* const* d_in, const int* in_sizes, int n_in,
                              void* d_out, int out_size, void* d_ws, size_t ws_size,
                              hipStream_t stream) {
    const float* x = (const float*)d_in[0];
    const float* e = (const float*)d_in[1];
    float* out = (float*)d_out;

    spatial_loss_fused<<<dim3(512), dim3(512), 0, stream>>>(x, e, out);
}